// Round 4
// baseline (355.261 us; speedup 1.0000x reference)
//
#include <hip/hip_runtime.h>
#include <stdint.h>

// B=2, T=2048, DIM=1024, H=16, HD=64. Device tensors FLOAT32; internally
// convert to bf16 once and run bf16-MFMA pipeline; final GEMM writes f32.
//
// ws (40MB): xb@0 (8MB), wb@8MB (4x2MB), Kb@16MB [4096,1024],
// VT@24MB [32 bh][64 d][2048 t]  (V^T written directly by the V-proj GEMM),
// Ob@32MB [4096,1024]. Qb (bf16 8MB) lives in d_out's first half (dead
// before the final projection overwrites d_out).

#define T_SEQ 2048

typedef unsigned short u16;
typedef __attribute__((ext_vector_type(8))) __bf16 bf16x8;   // MFMA A/B frag
typedef __attribute__((ext_vector_type(4))) float  f32x4;    // MFMA C/D frag

#define NEG_BIG (-30000.0f)

__device__ __forceinline__ u16 f2bf(float x) {
    union { float f; unsigned u; } c; c.f = x;
    return (u16)((c.u + 0x7fffu + ((c.u >> 16) & 1u)) >> 16);
}

__device__ __forceinline__ void gload_lds16(const void* g, void* l) {
    __builtin_amdgcn_global_load_lds(
        (const __attribute__((address_space(1))) void*)g,
        (__attribute__((address_space(3))) void*)l, 16, 0, 0);
}

__device__ __forceinline__ void storeC(u16* p, float v)   { *p = f2bf(v); }
__device__ __forceinline__ void storeC(float* p, float v) { *p = v; }

// ---------------------------------------------------------------------------
__global__ __launch_bounds__(256) void cvt_f32_bf16(
    const float* __restrict__ src, u16* __restrict__ dst, int n4)
{
    int i = blockIdx.x * 256 + threadIdx.x;
    if (i < n4) {
        float4 v = ((const float4*)src)[i];
        ushort4 o;
        o.x = f2bf(v.x); o.y = f2bf(v.y); o.z = f2bf(v.z); o.w = f2bf(v.w);
        ((ushort4*)dst)[i] = o;
    }
}

// ---------------------------------------------------------------------------
// GEMM: C[4096][1024] = A @ W^T (bf16, both K-contiguous). m97 structure:
// 128x128 tile, BK=64, 4 waves, linear LDS, global_load_lds width=16.
// VT_MODE: if OutT==u16 and blockIdx.z==2, write C transposed per-head into
// VT[bh][d][t] (the V^T slab) instead of row-major.
// ---------------------------------------------------------------------------
template <typename OutT, bool VT_MODE>
__global__ __launch_bounds__(256) void gemm_bt(
    const u16* __restrict__ A, const u16* __restrict__ Wb,
    OutT* __restrict__ C0, OutT* __restrict__ C1, OutT* __restrict__ C2)
{
    __shared__ __align__(16) char As[128 * 128];
    __shared__ __align__(16) char Bs[128 * 128];

    const u16* W = Wb + (size_t)blockIdx.z * 1048576u;
    OutT* Cz = blockIdx.z == 0 ? C0 : (blockIdx.z == 1 ? C1 : C2);

    const int tid = threadIdx.x;
    const int w = tid >> 6, l = tid & 63;
    const int wy = w >> 1, wx = w & 1;
    const int bm = blockIdx.y * 128, bn = blockIdx.x * 128;

    f32x4 acc[4][4];
#pragma unroll
    for (int m = 0; m < 4; m++)
#pragma unroll
        for (int n = 0; n < 4; n++) acc[m][n] = (f32x4){0.f, 0.f, 0.f, 0.f};

    const int lrow = l >> 3, lslot = l & 7;

    for (int kt = 0; kt < 16; ++kt) {
#pragma unroll
        for (int c = 0; c < 4; ++c) {
            int ch = w * 4 + c;
            int row = ch * 8 + lrow;
            gload_lds16((const char*)A + ((size_t)(bm + row) * 1024 + kt * 64) * 2 + lslot * 16,
                        As + ch * 1024);
            gload_lds16((const char*)W + ((size_t)(bn + row) * 1024 + kt * 64) * 2 + lslot * 16,
                        Bs + ch * 1024);
        }
        __syncthreads();

#pragma unroll
        for (int kk = 0; kk < 2; ++kk) {
            const int cb = (kk * 32 + (l >> 4) * 8) * 2;
            bf16x8 af[4], bfr[4];
#pragma unroll
            for (int m = 0; m < 4; m++)
                af[m] = *(const bf16x8*)(As + (wy * 64 + m * 16 + (l & 15)) * 128 + cb);
#pragma unroll
            for (int n = 0; n < 4; n++)
                bfr[n] = *(const bf16x8*)(Bs + (wx * 64 + n * 16 + (l & 15)) * 128 + cb);
#pragma unroll
            for (int m = 0; m < 4; m++)
#pragma unroll
                for (int n = 0; n < 4; n++)
                    acc[m][n] = __builtin_amdgcn_mfma_f32_16x16x32_bf16(
                        af[m], bfr[n], acc[m][n], 0, 0, 0);
        }
        __syncthreads();
    }

    // C/D layout: col = l&15, row = (l>>4)*4 + r
    const bool vtw = VT_MODE && (blockIdx.z == 2);
#pragma unroll
    for (int m = 0; m < 4; m++) {
        int grow0 = bm + wy * 64 + m * 16 + (l >> 4) * 4;
#pragma unroll
        for (int n = 0; n < 4; n++) {
            int gcol = bn + wx * 64 + n * 16 + (l & 15);
            if (vtw) {
                // V^T: VT[(b*16+h)*64 + d][t],  h=gcol>>6, d=gcol&63
                int bh = (grow0 >> 11) * 16 + (gcol >> 6);
                size_t rowbase = ((size_t)bh * 64 + (gcol & 63)) * T_SEQ + (grow0 & 2047);
#pragma unroll
                for (int r = 0; r < 4; r++)
                    storeC(&Cz[rowbase + r], acc[m][n][r]);
            } else {
#pragma unroll
                for (int r = 0; r < 4; r++)
                    storeC(&Cz[(size_t)(grow0 + r) * 1024 + gcol], acc[m][n][r]);
            }
        }
    }
}

// ---------------------------------------------------------------------------
// Flash attention, causal. Q,K bf16 [B*T,1024] slabs (head h at col h*64);
// V^T bf16 [bh][64][2048]. Block = (bh, yq); 4 waves x 16 q-rows, KVBLK=64.
// K and V^T fragments read DIRECTLY from global (L2-resident; one bh maps to
// one XCD since gridDim.x=32 and linear%8 = bh%8). No __syncthreads at all.
// ---------------------------------------------------------------------------
__global__ __launch_bounds__(256) void attn_fwd(
    const u16* __restrict__ Q, const u16* __restrict__ K,
    const u16* __restrict__ VT, u16* __restrict__ O)
{
    __shared__ __align__(16) u16 Ps[4][16][72];    // per-wave P

    const int bh = blockIdx.x;                     // 0..31 (b*16+h)
    const int yq = blockIdx.y;                     // heavy/light interleave
    const int qt = (yq & 1) ? (31 - (yq >> 1)) : (yq >> 1);
    const int b = bh >> 4, h = bh & 15;
    const int tid = threadIdx.x, w = tid >> 6, l = tid & 63;
    const size_t base = (size_t)b * T_SEQ * 1024 + h * 64;
    const u16* vtb = VT + (size_t)bh * 64 * T_SEQ;

    // Q fragments for the whole KV loop. A-frag: row=l&15, k=(l>>4)*8+e
    const int qrow = qt * 64 + w * 16 + (l & 15);
    const u16* qp = Q + base + (size_t)qrow * 1024 + (l >> 4) * 8;
    bf16x8 qf[2];
    qf[0] = *(const bf16x8*)(qp);
    qf[1] = *(const bf16x8*)(qp + 32);

    f32x4 oacc[4];
#pragma unroll
    for (int n = 0; n < 4; n++) oacc[n] = (f32x4){0.f, 0.f, 0.f, 0.f};
    float mrun[4], lrun[4];
#pragma unroll
    for (int r = 0; r < 4; r++) { mrun[r] = NEG_BIG; lrun[r] = 0.f; }

    const int qg = qt * 64 + w * 16;

    for (int kt = 0; kt <= qt; ++kt) {
        // ---- S = Q K^T, K B-frags from global (contiguous 16B, L2-hit)
        f32x4 s[4];
#pragma unroll
        for (int n = 0; n < 4; n++) s[n] = (f32x4){0.f, 0.f, 0.f, 0.f};
#pragma unroll
        for (int kk = 0; kk < 2; ++kk) {
#pragma unroll
            for (int nt = 0; nt < 4; ++nt) {
                bf16x8 kf = *(const bf16x8*)(K + base
                    + (size_t)(kt * 64 + nt * 16 + (l & 15)) * 1024
                    + kk * 32 + (l >> 4) * 8);
                s[nt] = __builtin_amdgcn_mfma_f32_16x16x32_bf16(qf[kk], kf, s[nt], 0, 0, 0);
            }
        }

        // ---- online softmax; lane holds rows (l>>4)*4+r, cols nt*16+(l&15)
        const int jb = kt * 64 + (l & 15);
#pragma unroll
        for (int r = 0; r < 4; ++r) {
            const int qrow_g = qg + (l >> 4) * 4 + r;
            float mt = NEG_BIG;
#pragma unroll
            for (int nt = 0; nt < 4; ++nt) {
                float v = (jb + nt * 16 > qrow_g) ? NEG_BIG : s[nt][r] * 0.125f;
                s[nt][r] = v;
                mt = fmaxf(mt, v);
            }
#pragma unroll
            for (int d = 1; d < 16; d <<= 1) mt = fmaxf(mt, __shfl_xor(mt, d));
            float mnew = fmaxf(mrun[r], mt);
            float alpha = __expf(mrun[r] - mnew);
            mrun[r] = mnew;
            float rs = 0.f;
#pragma unroll
            for (int nt = 0; nt < 4; ++nt) {
                float p = __expf(s[nt][r] - mnew);
                s[nt][r] = p;
                rs += p;
            }
#pragma unroll
            for (int d = 1; d < 16; d <<= 1) rs += __shfl_xor(rs, d);
            lrun[r] = lrun[r] * alpha + rs;
#pragma unroll
            for (int nt = 0; nt < 4; ++nt) oacc[nt][r] *= alpha;
        }

        // ---- P -> per-wave LDS (bf16); same-wave write->read, no barrier
#pragma unroll
        for (int nt = 0; nt < 4; ++nt)
#pragma unroll
            for (int r = 0; r < 4; ++r)
                Ps[w][(l >> 4) * 4 + r][nt * 16 + (l & 15)] = f2bf(s[nt][r]);

        // ---- O += P V   (B-frag = V^T rows, contiguous 16B from global)
#pragma unroll
        for (int kk = 0; kk < 2; ++kk) {
            bf16x8 pf = *(const bf16x8*)(&Ps[w][l & 15][kk * 32 + (l >> 4) * 8]);
#pragma unroll
            for (int nt = 0; nt < 4; ++nt) {
                bf16x8 vf = *(const bf16x8*)(vtb
                    + (size_t)(nt * 16 + (l & 15)) * T_SEQ
                    + kt * 64 + kk * 32 + (l >> 4) * 8);
                oacc[nt] = __builtin_amdgcn_mfma_f32_16x16x32_bf16(pf, vf, oacc[nt], 0, 0, 0);
            }
        }
    }

    // ---- epilogue: O /= l
#pragma unroll
    for (int nt = 0; nt < 4; ++nt) {
        int gcol = h * 64 + nt * 16 + (l & 15);
#pragma unroll
        for (int r = 0; r < 4; ++r) {
            int row = qt * 64 + w * 16 + (l >> 4) * 4 + r;
            O[(size_t)b * T_SEQ * 1024 + (size_t)row * 1024 + gcol] = f2bf(oacc[nt][r] / lrun[r]);
        }
    }
}

// ---------------------------------------------------------------------------
extern "C" void kernel_launch(void* const* d_in, const int* in_sizes, int n_in,
                              void* d_out, int out_size, void* d_ws, size_t ws_size,
                              hipStream_t stream)
{
    (void)in_sizes; (void)n_in; (void)out_size; (void)ws_size;
    const float* x  = (const float*)d_in[0];
    const float* wq = (const float*)d_in[1];
    const float* wk = (const float*)d_in[2];
    const float* wv = (const float*)d_in[3];
    const float* wo = (const float*)d_in[4];
    float* out = (float*)d_out;

    char* ws = (char*)d_ws;
    u16* xb = (u16*)(ws);                    // x bf16, 8MB
    u16* wb = (u16*)(ws + (8u << 20));       // wq,wk,wv,wo bf16
    u16* Kb = (u16*)(ws + (16u << 20));      // [4096,1024]
    u16* VT = (u16*)(ws + (24u << 20));      // [32][64][2048] V^T
    u16* Ob = (u16*)(ws + (32u << 20));      // [4096,1024]
    u16* Qb = (u16*)d_out;                   // Q bf16 in d_out's first 8MB

    dim3 blk(256);
    cvt_f32_bf16<<<4096, blk, 0, stream>>>(x, xb, 1048576);
    cvt_f32_bf16<<<1024, blk, 0, stream>>>(wq, wb + 0u * 1048576u, 262144);
    cvt_f32_bf16<<<1024, blk, 0, stream>>>(wk, wb + 1u * 1048576u, 262144);
    cvt_f32_bf16<<<1024, blk, 0, stream>>>(wv, wb + 2u * 1048576u, 262144);
    cvt_f32_bf16<<<1024, blk, 0, stream>>>(wo, wb + 3u * 1048576u, 262144);

    // Q,K = row-major; V written transposed into VT
    gemm_bt<u16, true><<<dim3(8, 32, 3), blk, 0, stream>>>(xb, wb, Qb, Kb, VT);
    // causal flash attention; x=bh pins each (b,h) to one XCD
    attn_fwd<<<dim3(32, 32, 1), blk, 0, stream>>>(Qb, Kb, VT, Ob);
    // out = O @ wo^T (f32)
    gemm_bt<float, false><<<dim3(8, 32, 1), blk, 0, stream>>>(Ob, wb + 3u * 1048576u,
                                                              out, out, out);
}

// Round 5
// 312.555 us; speedup vs baseline: 1.1366x; 1.1366x over previous
//
#include <hip/hip_runtime.h>
#include <stdint.h>

// B=2, T=2048, DIM=1024, H=16, HD=64. Device tensors FLOAT32; internally
// convert to bf16 once and run bf16-MFMA pipeline; final GEMM writes f32.
//
// ws (40MB): xb@0 (8MB), wb@8MB (4x2MB), Kb@16MB [4096,1024],
// VT@24MB [32 bh][64 d][2048 t] (V^T written by the V-proj GEMM epilogue),
// Ob@32MB [4096,1024]. Qb (bf16 8MB) lives in d_out's first half.

#define T_SEQ 2048

typedef unsigned short u16;
typedef __attribute__((ext_vector_type(8))) __bf16 bf16x8;   // MFMA A/B frag
typedef __attribute__((ext_vector_type(4))) float  f32x4;    // MFMA C/D frag

#define NEG_BIG (-30000.0f)

__device__ __forceinline__ u16 f2bf(float x) {
    union { float f; unsigned u; } c; c.f = x;
    return (u16)((c.u + 0x7fffu + ((c.u >> 16) & 1u)) >> 16);
}

__device__ __forceinline__ void gload_lds16(const void* g, void* l) {
    __builtin_amdgcn_global_load_lds(
        (const __attribute__((address_space(1))) void*)g,
        (__attribute__((address_space(3))) void*)l, 16, 0, 0);
}

__device__ __forceinline__ void storeC(u16* p, float v)   { *p = f2bf(v); }
__device__ __forceinline__ void storeC(float* p, float v) { *p = v; }

// ---------------------------------------------------------------------------
__global__ __launch_bounds__(256) void cvt_f32_bf16(
    const float* __restrict__ src, u16* __restrict__ dst, int n4)
{
    int i = blockIdx.x * 256 + threadIdx.x;
    if (i < n4) {
        float4 v = ((const float4*)src)[i];
        ushort4 o;
        o.x = f2bf(v.x); o.y = f2bf(v.y); o.z = f2bf(v.z); o.w = f2bf(v.w);
        ((ushort4*)dst)[i] = o;
    }
}

// ---------------------------------------------------------------------------
// GEMM: C[4096][1024] = A @ W^T (bf16, both K-contiguous). m97 structure.
// VT_MODE: blockIdx.z==2 writes C transposed per-head into VT[bh][d][t].
// ---------------------------------------------------------------------------
template <typename OutT, bool VT_MODE>
__global__ __launch_bounds__(256) void gemm_bt(
    const u16* __restrict__ A, const u16* __restrict__ Wb,
    OutT* __restrict__ C0, OutT* __restrict__ C1, OutT* __restrict__ C2)
{
    __shared__ __align__(16) char As[128 * 128];
    __shared__ __align__(16) char Bs[128 * 128];

    const u16* W = Wb + (size_t)blockIdx.z * 1048576u;
    OutT* Cz = blockIdx.z == 0 ? C0 : (blockIdx.z == 1 ? C1 : C2);

    const int tid = threadIdx.x;
    const int w = tid >> 6, l = tid & 63;
    const int wy = w >> 1, wx = w & 1;
    const int bm = blockIdx.y * 128, bn = blockIdx.x * 128;

    f32x4 acc[4][4];
#pragma unroll
    for (int m = 0; m < 4; m++)
#pragma unroll
        for (int n = 0; n < 4; n++) acc[m][n] = (f32x4){0.f, 0.f, 0.f, 0.f};

    const int lrow = l >> 3, lslot = l & 7;

    for (int kt = 0; kt < 16; ++kt) {
#pragma unroll
        for (int c = 0; c < 4; ++c) {
            int ch = w * 4 + c;
            int row = ch * 8 + lrow;
            gload_lds16((const char*)A + ((size_t)(bm + row) * 1024 + kt * 64) * 2 + lslot * 16,
                        As + ch * 1024);
            gload_lds16((const char*)W + ((size_t)(bn + row) * 1024 + kt * 64) * 2 + lslot * 16,
                        Bs + ch * 1024);
        }
        __syncthreads();

#pragma unroll
        for (int kk = 0; kk < 2; ++kk) {
            const int cb = (kk * 32 + (l >> 4) * 8) * 2;
            bf16x8 af[4], bfr[4];
#pragma unroll
            for (int m = 0; m < 4; m++)
                af[m] = *(const bf16x8*)(As + (wy * 64 + m * 16 + (l & 15)) * 128 + cb);
#pragma unroll
            for (int n = 0; n < 4; n++)
                bfr[n] = *(const bf16x8*)(Bs + (wx * 64 + n * 16 + (l & 15)) * 128 + cb);
#pragma unroll
            for (int m = 0; m < 4; m++)
#pragma unroll
                for (int n = 0; n < 4; n++)
                    acc[m][n] = __builtin_amdgcn_mfma_f32_16x16x32_bf16(
                        af[m], bfr[n], acc[m][n], 0, 0, 0);
        }
        __syncthreads();
    }

    const bool vtw = VT_MODE && (blockIdx.z == 2);
#pragma unroll
    for (int m = 0; m < 4; m++) {
        int grow0 = bm + wy * 64 + m * 16 + (l >> 4) * 4;
#pragma unroll
        for (int n = 0; n < 4; n++) {
            int gcol = bn + wx * 64 + n * 16 + (l & 15);
            if (vtw) {
                int bh = (grow0 >> 11) * 16 + (gcol >> 6);
                size_t rowbase = ((size_t)bh * 64 + (gcol & 63)) * T_SEQ + (grow0 & 2047);
#pragma unroll
                for (int r = 0; r < 4; r++)
                    storeC(&Cz[rowbase + r], acc[m][n][r]);
            } else {
#pragma unroll
                for (int r = 0; r < 4; r++)
                    storeC(&Cz[(size_t)(grow0 + r) * 1024 + gcol], acc[m][n][r]);
            }
        }
    }
}

// ---------------------------------------------------------------------------
// Flash attention, causal. ONE WAVE PER BLOCK (64 thr), QBLK=16 rows, KVBLK=64.
// Grid (32 bh, 128 qtiles) = 4096 blocks -> ~16 waves/CU resident (vs 8 in the
// 4-wave version) to hide the softmax/shuffle latency chain.
// K and V^T fragments straight from global (L2-resident, 16B contiguous).
// ---------------------------------------------------------------------------
__global__ __launch_bounds__(64) void attn_fwd(
    const u16* __restrict__ Q, const u16* __restrict__ K,
    const u16* __restrict__ VT, u16* __restrict__ O)
{
    __shared__ __align__(16) u16 Ps[16][72];       // this wave's P

    const int bh = blockIdx.x;                     // 0..31 (b*16+h)
    const int y = blockIdx.y;                      // 0..127 (16-row q tile)
    const int b = bh >> 4, h = bh & 15;
    const int l = threadIdx.x;                     // 0..63
    const size_t base = (size_t)b * T_SEQ * 1024 + h * 64;
    const u16* vtb = VT + (size_t)bh * 64 * T_SEQ;

    const int qg = y * 16;                         // first q row of this wave
    const int qrow = qg + (l & 15);
    const u16* qp = Q + base + (size_t)qrow * 1024 + (l >> 4) * 8;
    bf16x8 qf[2];
    qf[0] = *(const bf16x8*)(qp);
    qf[1] = *(const bf16x8*)(qp + 32);

    f32x4 oacc[4];
#pragma unroll
    for (int n = 0; n < 4; n++) oacc[n] = (f32x4){0.f, 0.f, 0.f, 0.f};
    float mrun[4], lrun[4];
#pragma unroll
    for (int r = 0; r < 4; r++) { mrun[r] = NEG_BIG; lrun[r] = 0.f; }

    const int ktmax = (qg + 15) >> 6;              // last 64-col tile touching rows

    for (int kt = 0; kt <= ktmax; ++kt) {
        // ---- S = Q K^T (skip fully-masked nt tiles: wave-uniform)
        f32x4 s[4];
#pragma unroll
        for (int n = 0; n < 4; n++) s[n] = (f32x4){0.f, 0.f, 0.f, 0.f};
#pragma unroll
        for (int kk = 0; kk < 2; ++kk) {
#pragma unroll
            for (int nt = 0; nt < 4; ++nt) {
                if (kt * 64 + nt * 16 <= qg + 15) {
                    bf16x8 kf = *(const bf16x8*)(K + base
                        + (size_t)(kt * 64 + nt * 16 + (l & 15)) * 1024
                        + kk * 32 + (l >> 4) * 8);
                    s[nt] = __builtin_amdgcn_mfma_f32_16x16x32_bf16(qf[kk], kf, s[nt], 0, 0, 0);
                }
            }
        }

        // ---- online softmax; lane holds rows (l>>4)*4+r, cols nt*16+(l&15)
        const int jb = kt * 64 + (l & 15);
#pragma unroll
        for (int r = 0; r < 4; ++r) {
            const int qrow_g = qg + (l >> 4) * 4 + r;
            float mt = NEG_BIG;
#pragma unroll
            for (int nt = 0; nt < 4; ++nt) {
                float v = (jb + nt * 16 > qrow_g) ? NEG_BIG : s[nt][r] * 0.125f;
                s[nt][r] = v;
                mt = fmaxf(mt, v);
            }
#pragma unroll
            for (int d = 1; d < 16; d <<= 1) mt = fmaxf(mt, __shfl_xor(mt, d));
            float mnew = fmaxf(mrun[r], mt);
            float alpha = __expf(mrun[r] - mnew);
            mrun[r] = mnew;
            float rs = 0.f;
#pragma unroll
            for (int nt = 0; nt < 4; ++nt) {
                float p = __expf(s[nt][r] - mnew);
                s[nt][r] = p;
                rs += p;
            }
#pragma unroll
            for (int d = 1; d < 16; d <<= 1) rs += __shfl_xor(rs, d);
            lrun[r] = lrun[r] * alpha + rs;
#pragma unroll
            for (int nt = 0; nt < 4; ++nt) oacc[nt][r] *= alpha;
        }

        // ---- P -> LDS (bf16); same-wave write->read, no barrier needed
#pragma unroll
        for (int nt = 0; nt < 4; ++nt)
#pragma unroll
            for (int r = 0; r < 4; ++r)
                Ps[(l >> 4) * 4 + r][nt * 16 + (l & 15)] = f2bf(s[nt][r]);

        // ---- O += P V (skip fully-masked k-slabs: wave-uniform)
#pragma unroll
        for (int kk = 0; kk < 2; ++kk) {
            if (kt * 64 + kk * 32 <= qg + 15) {
                bf16x8 pf = *(const bf16x8*)(&Ps[l & 15][kk * 32 + (l >> 4) * 8]);
#pragma unroll
                for (int nt = 0; nt < 4; ++nt) {
                    bf16x8 vf = *(const bf16x8*)(vtb
                        + (size_t)(nt * 16 + (l & 15)) * T_SEQ
                        + kt * 64 + kk * 32 + (l >> 4) * 8);
                    oacc[nt] = __builtin_amdgcn_mfma_f32_16x16x32_bf16(pf, vf, oacc[nt], 0, 0, 0);
                }
            }
        }
    }

    // ---- epilogue: O /= l
#pragma unroll
    for (int nt = 0; nt < 4; ++nt) {
        int gcol = h * 64 + nt * 16 + (l & 15);
#pragma unroll
        for (int r = 0; r < 4; ++r) {
            int row = qg + (l >> 4) * 4 + r;
            O[(size_t)b * T_SEQ * 1024 + (size_t)row * 1024 + gcol] = f2bf(oacc[nt][r] / lrun[r]);
        }
    }
}

// ---------------------------------------------------------------------------
extern "C" void kernel_launch(void* const* d_in, const int* in_sizes, int n_in,
                              void* d_out, int out_size, void* d_ws, size_t ws_size,
                              hipStream_t stream)
{
    (void)in_sizes; (void)n_in; (void)out_size; (void)ws_size;
    const float* x  = (const float*)d_in[0];
    const float* wq = (const float*)d_in[1];
    const float* wk = (const float*)d_in[2];
    const float* wv = (const float*)d_in[3];
    const float* wo = (const float*)d_in[4];
    float* out = (float*)d_out;

    char* ws = (char*)d_ws;
    u16* xb = (u16*)(ws);                    // x bf16, 8MB
    u16* wb = (u16*)(ws + (8u << 20));       // wq,wk,wv,wo bf16
    u16* Kb = (u16*)(ws + (16u << 20));      // [4096,1024]
    u16* VT = (u16*)(ws + (24u << 20));      // [32][64][2048] V^T
    u16* Ob = (u16*)(ws + (32u << 20));      // [4096,1024]
    u16* Qb = (u16*)d_out;                   // Q bf16 in d_out's first 8MB

    dim3 blk(256);
    cvt_f32_bf16<<<4096, blk, 0, stream>>>(x, xb, 1048576);
    cvt_f32_bf16<<<1024, blk, 0, stream>>>(wq, wb + 0u * 1048576u, 262144);
    cvt_f32_bf16<<<1024, blk, 0, stream>>>(wk, wb + 1u * 1048576u, 262144);
    cvt_f32_bf16<<<1024, blk, 0, stream>>>(wv, wb + 2u * 1048576u, 262144);
    cvt_f32_bf16<<<1024, blk, 0, stream>>>(wo, wb + 3u * 1048576u, 262144);

    // Q,K row-major; V written transposed into VT
    gemm_bt<u16, true><<<dim3(8, 32, 3), blk, 0, stream>>>(xb, wb, Qb, Kb, VT);
    // causal flash attention: 1-wave blocks, 16 q-rows each
    attn_fwd<<<dim3(32, 128, 1), dim3(64), 0, stream>>>(Qb, Kb, VT, Ob);
    // out = O @ wo^T (f32)
    gemm_bt<float, false><<<dim3(8, 32, 1), blk, 0, stream>>>(Ob, wb + 3u * 1048576u,
                                                              out, out, out);
}